// Round 1
// baseline (517.293 us; speedup 1.0000x reference)
//
#include <hip/hip_runtime.h>
#include <math.h>
#include <float.h>

#define KT 32
#define BT 64
#define MT 64
#define AS_STRIDE 68   // 64 + 4 pad: keeps float4 alignment, 4-way (cheap) store conflicts
#define NEG_TOPK 10

__device__ __forceinline__ void topk_insert(float (&top)[NEG_TOPK], float v) {
    if (v <= top[NEG_TOPK - 1]) return;
    int p = NEG_TOPK - 1;
    while (p > 0 && top[p - 1] < v) { top[p] = top[p - 1]; --p; }
    top[p] = v;
}

// Pass 1: tiled fp32 GEMM (64x64 tile, 4x4 per-thread) + fused mask ->
// per-(row, m-chunk) top-10 partials and positive-loss partials.
__global__ __launch_bounds__(256) void cl_pass1(
    const float* __restrict__ A,    // [B, D] inputs_col
    const float* __restrict__ Bm,   // [M, D] inputs_row
    const int* __restrict__ tcol,   // [B]
    const int* __restrict__ trow,   // [M]
    float* __restrict__ part_topk,  // [B, numMB, 10]
    float* __restrict__ pos_part,   // [B, numMB]
    int Bn, int M, int D, int numMB)
{
    __shared__ float smem[2 * KT * AS_STRIDE];
    __shared__ int tcs[BT];
    __shared__ int trs[MT];
    float (*As)[AS_STRIDE] = reinterpret_cast<float (*)[AS_STRIDE]>(smem);
    float (*Bs)[AS_STRIDE] = reinterpret_cast<float (*)[AS_STRIDE]>(smem + KT * AS_STRIDE);

    const int mb = blockIdx.x;
    const int bi = blockIdx.y;
    const int i0 = bi * BT, j0 = mb * MT;
    const int t = threadIdx.x;
    const int tx = t & 15, ty = t >> 4;

    if (t < BT) tcs[t] = tcol[i0 + t];
    else if (t < BT + MT) trs[t - BT] = trow[j0 + t - BT];

    float acc[4][4] = {};

    const int rr = t >> 5;   // 0..7
    const int kk = t & 31;   // 0..31

    for (int k0 = 0; k0 < D; k0 += KT) {
        #pragma unroll
        for (int p = 0; p < 8; ++p) {
            int r = rr + p * 8;
            As[kk][r] = A[(size_t)(i0 + r) * D + k0 + kk];
            Bs[kk][r] = Bm[(size_t)(j0 + r) * D + k0 + kk];
        }
        __syncthreads();
        #pragma unroll
        for (int k = 0; k < KT; ++k) {
            float4 a4 = *reinterpret_cast<const float4*>(&As[k][ty * 4]);
            float4 b4 = *reinterpret_cast<const float4*>(&Bs[k][tx * 4]);
            float aa[4] = {a4.x, a4.y, a4.z, a4.w};
            float bb[4] = {b4.x, b4.y, b4.z, b4.w};
            #pragma unroll
            for (int r = 0; r < 4; ++r)
                #pragma unroll
                for (int c = 0; c < 4; ++c)
                    acc[r][c] = fmaf(aa[r], bb[c], acc[r][c]);
        }
        __syncthreads();
    }

    // Phase 2: dump raw sims to LDS (reuse staging buffers), then one thread
    // per row scans 64 cols: masked pos accumulation + local top-10.
    float* simt = smem;  // [BT][65] = 4160 floats <= 4352 available
    #pragma unroll
    for (int r = 0; r < 4; ++r)
        #pragma unroll
        for (int c = 0; c < 4; ++c)
            simt[(ty * 4 + r) * 65 + tx * 4 + c] = acc[r][c];
    __syncthreads();

    if (t < BT) {
        const int i = i0 + t;
        const int myc = tcs[t];
        float top[NEG_TOPK];
        #pragma unroll
        for (int q = 0; q < NEG_TOPK; ++q) top[q] = -INFINITY;
        float pos = 0.0f;
        for (int c = 0; c < MT; ++c) {
            float s = simt[t * 65 + c];
            if (myc == trs[c]) {
                if (s < 0.99999f) pos += 1.0f - s;
            } else {
                topk_insert(top, s);
            }
        }
        float* dst = part_topk + ((size_t)i * numMB + mb) * NEG_TOPK;
        #pragma unroll
        for (int q = 0; q < NEG_TOPK; ++q) dst[q] = top[q];
        pos_part[(size_t)i * numMB + mb] = pos;
    }
}

// Pass 2: one block per row. Merge numMB*10 top-k candidates -> top-10,
// sum finite; reduce pos partials; row_tot[i] = pos + neg.
__global__ __launch_bounds__(256) void cl_pass2(
    const float* __restrict__ part_topk,
    const float* __restrict__ pos_part,
    float* __restrict__ row_tot,
    int numMB)
{
    const int i = blockIdx.x;
    const int t = threadIdx.x;
    __shared__ float stop[256][NEG_TOPK];
    __shared__ float stop2[32][NEG_TOPK];
    __shared__ float red[256];

    const int n = numMB * NEG_TOPK;
    const float* src = part_topk + (size_t)i * n;
    float top[NEG_TOPK];
    #pragma unroll
    for (int q = 0; q < NEG_TOPK; ++q) top[q] = -INFINITY;
    for (int idx = t; idx < n; idx += 256) topk_insert(top, src[idx]);
    #pragma unroll
    for (int q = 0; q < NEG_TOPK; ++q) stop[t][q] = top[q];

    float pos = 0.0f;
    const float* psrc = pos_part + (size_t)i * numMB;
    for (int idx = t; idx < numMB; idx += 256) pos += psrc[idx];
    red[t] = pos;
    __syncthreads();

    // tree-reduce pos
    for (int s2 = 128; s2 >= 1; s2 >>= 1) {
        if (t < s2) red[t] += red[t + s2];
        __syncthreads();
    }

    // 256 lists -> 32 lists
    if (t < 32) {
        float m[NEG_TOPK];
        #pragma unroll
        for (int q = 0; q < NEG_TOPK; ++q) m[q] = -INFINITY;
        for (int l = 0; l < 8; ++l)
            for (int q = 0; q < NEG_TOPK; ++q) topk_insert(m, stop[t * 8 + l][q]);
        #pragma unroll
        for (int q = 0; q < NEG_TOPK; ++q) stop2[t][q] = m[q];
    }
    __syncthreads();

    if (t == 0) {
        float m[NEG_TOPK];
        #pragma unroll
        for (int q = 0; q < NEG_TOPK; ++q) m[q] = -INFINITY;
        for (int l = 0; l < 32; ++l)
            for (int q = 0; q < NEG_TOPK; ++q) topk_insert(m, stop2[l][q]);
        float neg = 0.0f;
        #pragma unroll
        for (int q = 0; q < NEG_TOPK; ++q)
            if (isfinite(m[q])) neg += m[q];
        row_tot[i] = neg + red[0];
    }
}

// Pass 3: mean over rows.
__global__ __launch_bounds__(256) void cl_pass3(
    const float* __restrict__ row_tot, float* __restrict__ out, int Bn)
{
    __shared__ float red[256];
    const int t = threadIdx.x;
    float v = 0.0f;
    for (int idx = t; idx < Bn; idx += 256) v += row_tot[idx];
    red[t] = v;
    __syncthreads();
    for (int s2 = 128; s2 >= 1; s2 >>= 1) {
        if (t < s2) red[t] += red[t + s2];
        __syncthreads();
    }
    if (t == 0) out[0] = red[0] / (float)Bn;
}

extern "C" void kernel_launch(void* const* d_in, const int* in_sizes, int n_in,
                              void* d_out, int out_size, void* d_ws, size_t ws_size,
                              hipStream_t stream)
{
    const float* A    = (const float*)d_in[0];  // inputs_col [B,D]
    const int*   tcol = (const int*)d_in[1];    // targets_col [B]
    const float* Bm   = (const float*)d_in[2];  // inputs_row [M,D]
    const int*   trow = (const int*)d_in[3];    // target_row [M]
    float* out = (float*)d_out;

    const int Bn = in_sizes[1];
    const int M  = in_sizes[3];
    const int D  = in_sizes[0] / Bn;
    const int numMB = M / MT;

    float* part_topk = (float*)d_ws;                                    // B*numMB*10
    float* pos_part  = part_topk + (size_t)Bn * numMB * NEG_TOPK;       // B*numMB
    float* row_tot   = pos_part + (size_t)Bn * numMB;                   // B

    dim3 g1(numMB, Bn / BT);
    cl_pass1<<<g1, 256, 0, stream>>>(A, Bm, tcol, trow, part_topk, pos_part,
                                     Bn, M, D, numMB);
    cl_pass2<<<Bn, 256, 0, stream>>>(part_topk, pos_part, row_tot, numMB);
    cl_pass3<<<1, 256, 0, stream>>>(row_tot, out, Bn);
}

// Round 2
// 325.557 us; speedup vs baseline: 1.5889x; 1.5889x over previous
//
#include <hip/hip_runtime.h>
#include <math.h>
#include <float.h>

typedef __attribute__((ext_vector_type(4))) float f32x4;
typedef __attribute__((ext_vector_type(8))) __bf16 bf16x8;
typedef __attribute__((ext_vector_type(4))) __bf16 bf16x4;

#define NEG_TOPK 10
#define BROW 256      // B (output rows), full per block
#define MT 128        // output cols per block
#define BK 64         // K-step
#define SIMSTR 129    // f32 stride for sims buffer (bank-stride 1)

__device__ __forceinline__ void topk_insert(float (&top)[NEG_TOPK], float v) {
    if (v <= top[NEG_TOPK - 1]) return;
    int p = NEG_TOPK - 1;
    while (p > 0 && top[p - 1] < v) { top[p] = top[p - 1]; --p; }
    top[p] = v;
}

__device__ __forceinline__ bf16x4 cvt4(float4 v) {
    bf16x4 r;
    r[0] = (__bf16)v.x; r[1] = (__bf16)v.y;
    r[2] = (__bf16)v.z; r[3] = (__bf16)v.w;
    return r;
}

// Pass 1: bf16 MFMA GEMM (256x128 tile, 8 waves of 64x64) + fused epilogue:
// per-(row, 128-col chunk) top-10 partials and positive-loss partials.
__global__ __launch_bounds__(512, 2) void cl_pass1(
    const float* __restrict__ A,    // [256, D] inputs_col fp32
    const float* __restrict__ Bm,   // [M, D]  inputs_row fp32
    const int* __restrict__ tcol,   // [256]
    const int* __restrict__ trow,   // [M]
    float* __restrict__ part_topk,  // [256, numMB, 10]
    float* __restrict__ pos_part,   // [256, numMB]
    int D, int numMB)
{
    // sims buffer (129 KB) aliases the staging tiles (A: 32 KB, B: 16 KB).
    __shared__ float sims[BROW * SIMSTR];
    __shared__ int trs[MT];
    char* Ab = (char*)sims;                 // A tile [256 rows][128 B] bf16, swizzled
    char* Bb = Ab + BROW * BK * 2;          // B tile [128 rows][128 B] bf16, swizzled

    const int mb = blockIdx.x;
    const int j0 = mb * MT;
    const int t  = threadIdx.x;
    const int wave = t >> 6, lane = t & 63;
    const int wr = wave >> 1, wc = wave & 1;   // 4x2 wave grid, wave tile 64x64
    const int lrow = lane & 15, lk = lane >> 4;

    if (t < MT) trs[t] = trow[j0 + t];

    const float4* A4 = (const float4*)A;
    const float4* B4 = (const float4*)Bm;
    const int ldq = D >> 2;   // 128 float4 per row

    f32x4 acc[4][4];
    #pragma unroll
    for (int m = 0; m < 4; ++m)
        #pragma unroll
        for (int n = 0; n < 4; ++n)
            acc[m][n] = (f32x4){0.f, 0.f, 0.f, 0.f};

    float4 ar[8];  // A staging: 8 float4/thread (256x64 fp32)
    float4 br[4];  // B staging: 4 float4/thread (128x64 fp32)
    #pragma unroll
    for (int s = 0; s < 8; ++s) {
        int f = s * 512 + t; int r = f >> 4, k4 = f & 15;
        ar[s] = A4[r * ldq + k4];
    }
    #pragma unroll
    for (int s = 0; s < 4; ++s) {
        int f = s * 512 + t; int r = f >> 4, k4 = f & 15;
        br[s] = B4[(size_t)(j0 + r) * ldq + k4];
    }

    const int NSTEP = D / BK;   // 8
    for (int step = 0; step < NSTEP; ++step) {
        // stage regs -> LDS as bf16, XOR-swizzled (row stride 128 B)
        #pragma unroll
        for (int s = 0; s < 8; ++s) {
            int f = s * 512 + t; int r = f >> 4, k4 = f & 15;
            int off = r * 128 + ((k4 * 8) ^ ((r & 7) << 4));
            *(bf16x4*)(Ab + off) = cvt4(ar[s]);
        }
        #pragma unroll
        for (int s = 0; s < 4; ++s) {
            int f = s * 512 + t; int r = f >> 4, k4 = f & 15;
            int off = r * 128 + ((k4 * 8) ^ ((r & 7) << 4));
            *(bf16x4*)(Bb + off) = cvt4(br[s]);
        }
        __syncthreads();

        // issue next tile's global loads early (T14: latency hides under MFMA)
        if (step + 1 < NSTEP) {
            int kq = (step + 1) * (BK / 4);
            #pragma unroll
            for (int s = 0; s < 8; ++s) {
                int f = s * 512 + t; int r = f >> 4, k4 = f & 15;
                ar[s] = A4[r * ldq + kq + k4];
            }
            #pragma unroll
            for (int s = 0; s < 4; ++s) {
                int f = s * 512 + t; int r = f >> 4, k4 = f & 15;
                br[s] = B4[(size_t)(j0 + r) * ldq + kq + k4];
            }
        }

        // compute: 2 K=32 slices, 16 MFMA each
        const int swz = (lrow & 7) << 4;
        #pragma unroll
        for (int ks = 0; ks < 2; ++ks) {
            bf16x8 af[4], bfr[4];
            const int kb = ks * 64 + lk * 16;
            #pragma unroll
            for (int m = 0; m < 4; ++m) {
                int row = wr * 64 + m * 16 + lrow;
                af[m] = *(const bf16x8*)(Ab + row * 128 + (kb ^ swz));
            }
            #pragma unroll
            for (int n = 0; n < 4; ++n) {
                int row = wc * 64 + n * 16 + lrow;
                bfr[n] = *(const bf16x8*)(Bb + row * 128 + (kb ^ swz));
            }
            #pragma unroll
            for (int m = 0; m < 4; ++m)
                #pragma unroll
                for (int n = 0; n < 4; ++n)
                    acc[m][n] = __builtin_amdgcn_mfma_f32_16x16x32_bf16(
                        af[m], bfr[n], acc[m][n], 0, 0, 0);
        }
        __syncthreads();
    }

    // epilogue: acc -> sims (stride 129 => bank-stride 1, ~2-way max)
    #pragma unroll
    for (int m = 0; m < 4; ++m)
        #pragma unroll
        for (int n = 0; n < 4; ++n)
            #pragma unroll
            for (int r = 0; r < 4; ++r) {
                int row = wr * 64 + m * 16 + lk * 4 + r;
                int col = wc * 64 + n * 16 + lrow;
                sims[row * SIMSTR + col] = acc[m][n][r];
            }
    __syncthreads();

    // fused scan: 2 threads per row, 64 cols each
    {
        const int row = t >> 1, half = t & 1;
        const int myc = tcol[row];
        float top[NEG_TOPK];
        #pragma unroll
        for (int q = 0; q < NEG_TOPK; ++q) top[q] = -INFINITY;
        float pos = 0.f;
        const float* srow = &sims[row * SIMSTR + half * 64];
        const int* lab = &trs[half * 64];
        for (int c = 0; c < 64; ++c) {
            float s = srow[c];
            if (myc == lab[c]) { if (s < 0.99999f) pos += 1.f - s; }
            else topk_insert(top, s);
        }
        __syncthreads();   // all scans done; sims region reusable
        float* mtop = sims;
        #pragma unroll
        for (int q = 0; q < NEG_TOPK; ++q) mtop[t * NEG_TOPK + q] = top[q];
        mtop[512 * NEG_TOPK + t] = pos;
        __syncthreads();
        if (half == 0) {
            const float* ot = &mtop[(t + 1) * NEG_TOPK];
            #pragma unroll
            for (int q = 0; q < NEG_TOPK; ++q) topk_insert(top, ot[q]);
            float post = pos + mtop[512 * NEG_TOPK + t + 1];
            float* dst = part_topk + ((size_t)row * numMB + mb) * NEG_TOPK;
            #pragma unroll
            for (int q = 0; q < NEG_TOPK; ++q) dst[q] = top[q];
            pos_part[(size_t)row * numMB + mb] = post;
        }
    }
}

// Pass 2: one block per row. Merge numMB*10 candidates -> top-10, sum finite;
// reduce pos partials; row_tot[i] = pos + neg.
__global__ __launch_bounds__(256) void cl_pass2(
    const float* __restrict__ part_topk,
    const float* __restrict__ pos_part,
    float* __restrict__ row_tot,
    int numMB)
{
    const int i = blockIdx.x;
    const int t = threadIdx.x;
    __shared__ float stop[256][NEG_TOPK];
    __shared__ float stop2[32][NEG_TOPK];
    __shared__ float red[256];

    const int n = numMB * NEG_TOPK;
    const float* src = part_topk + (size_t)i * n;
    float top[NEG_TOPK];
    #pragma unroll
    for (int q = 0; q < NEG_TOPK; ++q) top[q] = -INFINITY;
    for (int idx = t; idx < n; idx += 256) topk_insert(top, src[idx]);
    #pragma unroll
    for (int q = 0; q < NEG_TOPK; ++q) stop[t][q] = top[q];

    float pos = 0.0f;
    const float* psrc = pos_part + (size_t)i * numMB;
    for (int idx = t; idx < numMB; idx += 256) pos += psrc[idx];
    red[t] = pos;
    __syncthreads();

    for (int s2 = 128; s2 >= 1; s2 >>= 1) {
        if (t < s2) red[t] += red[t + s2];
        __syncthreads();
    }

    if (t < 32) {
        float m[NEG_TOPK];
        #pragma unroll
        for (int q = 0; q < NEG_TOPK; ++q) m[q] = -INFINITY;
        for (int l = 0; l < 8; ++l)
            for (int q = 0; q < NEG_TOPK; ++q) topk_insert(m, stop[t * 8 + l][q]);
        #pragma unroll
        for (int q = 0; q < NEG_TOPK; ++q) stop2[t][q] = m[q];
    }
    __syncthreads();

    if (t == 0) {
        float m[NEG_TOPK];
        #pragma unroll
        for (int q = 0; q < NEG_TOPK; ++q) m[q] = -INFINITY;
        for (int l = 0; l < 32; ++l)
            for (int q = 0; q < NEG_TOPK; ++q) topk_insert(m, stop2[l][q]);
        float neg = 0.0f;
        #pragma unroll
        for (int q = 0; q < NEG_TOPK; ++q)
            if (isfinite(m[q])) neg += m[q];
        row_tot[i] = neg + red[0];
    }
}

// Pass 3: mean over rows.
__global__ __launch_bounds__(256) void cl_pass3(
    const float* __restrict__ row_tot, float* __restrict__ out, int Bn)
{
    __shared__ float red[256];
    const int t = threadIdx.x;
    float v = 0.0f;
    for (int idx = t; idx < Bn; idx += 256) v += row_tot[idx];
    red[t] = v;
    __syncthreads();
    for (int s2 = 128; s2 >= 1; s2 >>= 1) {
        if (t < s2) red[t] += red[t + s2];
        __syncthreads();
    }
    if (t == 0) out[0] = red[0] / (float)Bn;
}

extern "C" void kernel_launch(void* const* d_in, const int* in_sizes, int n_in,
                              void* d_out, int out_size, void* d_ws, size_t ws_size,
                              hipStream_t stream)
{
    const float* A    = (const float*)d_in[0];  // inputs_col [B,D]
    const int*   tcol = (const int*)d_in[1];    // targets_col [B]
    const float* Bm   = (const float*)d_in[2];  // inputs_row [M,D]
    const int*   trow = (const int*)d_in[3];    // target_row [M]
    float* out = (float*)d_out;

    const int Bn = in_sizes[1];          // 256
    const int M  = in_sizes[3];          // 65536
    const int D  = in_sizes[0] / Bn;     // 512
    const int numMB = M / MT;            // 512

    float* part_topk = (float*)d_ws;                                // B*numMB*10
    float* pos_part  = part_topk + (size_t)Bn * numMB * NEG_TOPK;   // B*numMB
    float* row_tot   = pos_part + (size_t)Bn * numMB;               // B

    cl_pass1<<<numMB, 512, 0, stream>>>(A, Bm, tcol, trow, part_topk, pos_part,
                                        D, numMB);
    cl_pass2<<<Bn, 256, 0, stream>>>(part_topk, pos_part, row_tot, numMB);
    cl_pass3<<<1, 256, 0, stream>>>(row_tot, out, Bn);
}

// Round 3
// 256.579 us; speedup vs baseline: 2.0161x; 1.2688x over previous
//
#include <hip/hip_runtime.h>
#include <math.h>
#include <float.h>

typedef __attribute__((ext_vector_type(4))) float f32x4;
typedef __attribute__((ext_vector_type(8))) __bf16 bf16x8;
typedef __attribute__((ext_vector_type(4))) __bf16 bf16x4;

#define NEG_TOPK 10
#define BROW 256      // batch rows, full per block
#define MT 128        // output cols per block
#define BK 64         // K-step
#define SIMSTR 136    // bf16 stride for sims buffer (272 B, 16B-aligned)

// Branchless static-index top-k insert (sorted descending).
// new_top[q] = med3(v, top[q-1], top[q]); stays entirely in VGPRs (rule #20).
__device__ __forceinline__ void topk_ins(float (&top)[NEG_TOPK], float v) {
    #pragma unroll
    for (int q = NEG_TOPK - 1; q >= 1; --q)
        top[q] = fmaxf(fminf(v, top[q - 1]), top[q]);
    top[0] = fmaxf(top[0], v);
}

__device__ __forceinline__ bf16x4 cvt4(float4 v) {
    bf16x4 r;
    r[0] = (__bf16)v.x; r[1] = (__bf16)v.y;
    r[2] = (__bf16)v.z; r[3] = (__bf16)v.w;
    return r;
}

// Pass 1: bf16 MFMA GEMM (256x128 tile, 8 waves of 64x64) + fused epilogue:
// per-(row, 64-col chunk) top-10 partials and positive-loss partials.
__global__ __launch_bounds__(512, 2) void cl_pass1(
    const float* __restrict__ A,    // [256, D] inputs_col fp32
    const float* __restrict__ Bm,   // [M, D]  inputs_row fp32
    const int* __restrict__ tcol,   // [256]
    const int* __restrict__ trow,   // [M]
    float* __restrict__ part_topk,  // [256, nch, 10]   nch = 2*gridDim.x
    float* __restrict__ pos_part,   // [256, nch]
    int D)
{
    // sims bf16 [256][136] = 69,632 B; staging tiles (48 KB) alias its start.
    __shared__ unsigned short simsb[BROW * SIMSTR];
    __shared__ int trs[MT];
    char* Ab = (char*)simsb;            // A tile [256r][128 B] bf16, swizzled
    char* Bb = Ab + BROW * BK * 2;      // B tile [128r][128 B] bf16, swizzled

    const int mb = blockIdx.x;
    const int j0 = mb * MT;
    const int t  = threadIdx.x;
    const int wave = t >> 6, lane = t & 63;
    const int wr = wave >> 1, wc = wave & 1;   // 4x2 wave grid, wave tile 64x64
    const int lrow = lane & 15, lk = lane >> 4;

    if (t < MT) trs[t] = trow[j0 + t];

    const float4* A4 = (const float4*)A;
    const float4* B4 = (const float4*)Bm;
    const int ldq = D >> 2;   // float4 per row

    f32x4 acc[4][4];
    #pragma unroll
    for (int m = 0; m < 4; ++m)
        #pragma unroll
        for (int n = 0; n < 4; ++n)
            acc[m][n] = (f32x4){0.f, 0.f, 0.f, 0.f};

    float4 ar[8];  // A staging: 8 float4/thread (256x64 fp32)
    float4 br[4];  // B staging: 4 float4/thread (128x64 fp32)
    #pragma unroll
    for (int s = 0; s < 8; ++s) {
        int f = s * 512 + t; int r = f >> 4, k4 = f & 15;
        ar[s] = A4[r * ldq + k4];
    }
    #pragma unroll
    for (int s = 0; s < 4; ++s) {
        int f = s * 512 + t; int r = f >> 4, k4 = f & 15;
        br[s] = B4[(size_t)(j0 + r) * ldq + k4];
    }

    const int NSTEP = D / BK;   // 8
    for (int step = 0; step < NSTEP; ++step) {
        // stage regs -> LDS as bf16, XOR-swizzled (row stride 128 B)
        #pragma unroll
        for (int s = 0; s < 8; ++s) {
            int f = s * 512 + t; int r = f >> 4, k4 = f & 15;
            int off = r * 128 + ((k4 * 8) ^ ((r & 7) << 4));
            *(bf16x4*)(Ab + off) = cvt4(ar[s]);
        }
        #pragma unroll
        for (int s = 0; s < 4; ++s) {
            int f = s * 512 + t; int r = f >> 4, k4 = f & 15;
            int off = r * 128 + ((k4 * 8) ^ ((r & 7) << 4));
            *(bf16x4*)(Bb + off) = cvt4(br[s]);
        }
        __syncthreads();

        // issue next tile's global loads early (latency hides under MFMA)
        if (step + 1 < NSTEP) {
            int kq = (step + 1) * (BK / 4);
            #pragma unroll
            for (int s = 0; s < 8; ++s) {
                int f = s * 512 + t; int r = f >> 4, k4 = f & 15;
                ar[s] = A4[r * ldq + kq + k4];
            }
            #pragma unroll
            for (int s = 0; s < 4; ++s) {
                int f = s * 512 + t; int r = f >> 4, k4 = f & 15;
                br[s] = B4[(size_t)(j0 + r) * ldq + kq + k4];
            }
        }

        // compute: 2 K=32 slices, 16 MFMA each
        const int swz = (lrow & 7) << 4;
        #pragma unroll
        for (int ks = 0; ks < 2; ++ks) {
            bf16x8 af[4], bfr[4];
            const int kb = ks * 64 + lk * 16;
            #pragma unroll
            for (int m = 0; m < 4; ++m) {
                int row = wr * 64 + m * 16 + lrow;
                af[m] = *(const bf16x8*)(Ab + row * 128 + (kb ^ swz));
            }
            #pragma unroll
            for (int n = 0; n < 4; ++n) {
                int row = wc * 64 + n * 16 + lrow;
                bfr[n] = *(const bf16x8*)(Bb + row * 128 + (kb ^ swz));
            }
            #pragma unroll
            for (int m = 0; m < 4; ++m)
                #pragma unroll
                for (int n = 0; n < 4; ++n)
                    acc[m][n] = __builtin_amdgcn_mfma_f32_16x16x32_bf16(
                        af[m], bfr[n], acc[m][n], 0, 0, 0);
        }
        __syncthreads();
    }

    // epilogue: acc -> bf16 sims in LDS (aliases staging; all MFMA done+synced)
    #pragma unroll
    for (int m = 0; m < 4; ++m)
        #pragma unroll
        for (int n = 0; n < 4; ++n)
            #pragma unroll
            for (int r = 0; r < 4; ++r) {
                int row = wr * 64 + m * 16 + lk * 4 + r;
                int col = wc * 64 + n * 16 + lrow;
                __bf16 b = (__bf16)acc[m][n][r];
                simsb[row * SIMSTR + col] = *(unsigned short*)&b;
            }
    __syncthreads();

    // fused scan: 2 threads per row, 64 cols each; branchless med3 top-k
    {
        const int row = t >> 1, half = t & 1;
        const int myc = tcol[row];
        float top[NEG_TOPK];
        #pragma unroll
        for (int q = 0; q < NEG_TOPK; ++q) top[q] = -INFINITY;
        float pos = 0.f;
        const char* srow = (const char*)simsb + (row * SIMSTR + half * 64) * 2;
        #pragma unroll
        for (int j = 0; j < 8; ++j) {
            bf16x8 v8 = *(const bf16x8*)(srow + j * 16);
            #pragma unroll
            for (int e = 0; e < 8; ++e) {
                float s = (float)v8[e];
                bool same = (trs[half * 64 + j * 8 + e] == myc);
                pos += (same && s < 0.99999f) ? (1.f - s) : 0.f;
                topk_ins(top, same ? -INFINITY : s);
            }
        }
        const int ch = mb * 2 + half;   // 1024 chunks of 64 cols
        float* dst = part_topk + ((size_t)row * 1024 + ch) * NEG_TOPK;
        #pragma unroll
        for (int q = 0; q < NEG_TOPK; ++q) dst[q] = top[q];
        pos_part[(size_t)row * 1024 + ch] = pos;
    }
}

// Pass 2: one block per row. Merge nch*10 candidates -> top-10, sum finite;
// reduce pos partials; row_tot[i] = pos + neg.
__global__ __launch_bounds__(256) void cl_pass2(
    const float* __restrict__ part_topk,
    const float* __restrict__ pos_part,
    float* __restrict__ row_tot,
    int nch)
{
    const int i = blockIdx.x;
    const int t = threadIdx.x;
    __shared__ float stop[256][NEG_TOPK];
    __shared__ float stop2[32][NEG_TOPK];
    __shared__ float red[256];

    const int n = nch * NEG_TOPK;
    const float* src = part_topk + (size_t)i * n;
    float top[NEG_TOPK];
    #pragma unroll
    for (int q = 0; q < NEG_TOPK; ++q) top[q] = -INFINITY;
    for (int idx = t; idx < n; idx += 256) topk_ins(top, src[idx]);
    #pragma unroll
    for (int q = 0; q < NEG_TOPK; ++q) stop[t][q] = top[q];

    float pos = 0.0f;
    const float* psrc = pos_part + (size_t)i * nch;
    for (int idx = t; idx < nch; idx += 256) pos += psrc[idx];
    red[t] = pos;
    __syncthreads();

    for (int s2 = 128; s2 >= 1; s2 >>= 1) {
        if (t < s2) red[t] += red[t + s2];
        __syncthreads();
    }

    if (t < 32) {
        float m[NEG_TOPK];
        #pragma unroll
        for (int q = 0; q < NEG_TOPK; ++q) m[q] = -INFINITY;
        for (int l = 0; l < 8; ++l)
            #pragma unroll
            for (int q = 0; q < NEG_TOPK; ++q) topk_ins(m, stop[t * 8 + l][q]);
        #pragma unroll
        for (int q = 0; q < NEG_TOPK; ++q) stop2[t][q] = m[q];
    }
    __syncthreads();

    if (t == 0) {
        float m[NEG_TOPK];
        #pragma unroll
        for (int q = 0; q < NEG_TOPK; ++q) m[q] = -INFINITY;
        for (int l = 0; l < 32; ++l)
            #pragma unroll
            for (int q = 0; q < NEG_TOPK; ++q) topk_ins(m, stop2[l][q]);
        float neg = 0.0f;
        #pragma unroll
        for (int q = 0; q < NEG_TOPK; ++q)
            if (isfinite(m[q])) neg += m[q];
        row_tot[i] = neg + red[0];
    }
}

// Pass 3: mean over rows.
__global__ __launch_bounds__(256) void cl_pass3(
    const float* __restrict__ row_tot, float* __restrict__ out, int Bn)
{
    __shared__ float red[256];
    const int t = threadIdx.x;
    float v = 0.0f;
    for (int idx = t; idx < Bn; idx += 256) v += row_tot[idx];
    red[t] = v;
    __syncthreads();
    for (int s2 = 128; s2 >= 1; s2 >>= 1) {
        if (t < s2) red[t] += red[t + s2];
        __syncthreads();
    }
    if (t == 0) out[0] = red[0] / (float)Bn;
}

extern "C" void kernel_launch(void* const* d_in, const int* in_sizes, int n_in,
                              void* d_out, int out_size, void* d_ws, size_t ws_size,
                              hipStream_t stream)
{
    const float* A    = (const float*)d_in[0];  // inputs_col [B,D]
    const int*   tcol = (const int*)d_in[1];    // targets_col [B]
    const float* Bm   = (const float*)d_in[2];  // inputs_row [M,D]
    const int*   trow = (const int*)d_in[3];    // target_row [M]
    float* out = (float*)d_out;

    const int Bn = in_sizes[1];          // 256
    const int M  = in_sizes[3];          // 65536
    const int D  = in_sizes[0] / Bn;     // 512
    const int numMB = M / MT;            // 512 blocks
    const int nch = numMB * 2;           // 1024 chunks of 64 cols

    float* part_topk = (float*)d_ws;                              // B*nch*10
    float* pos_part  = part_topk + (size_t)Bn * nch * NEG_TOPK;   // B*nch
    float* row_tot   = pos_part + (size_t)Bn * nch;               // B

    cl_pass1<<<numMB, 512, 0, stream>>>(A, Bm, tcol, trow, part_topk, pos_part, D);
    cl_pass2<<<Bn, 256, 0, stream>>>(part_topk, pos_part, row_tot, nch);
    cl_pass3<<<1, 256, 0, stream>>>(row_tot, out, Bn);
}